// Round 1
// baseline (843.181 us; speedup 1.0000x reference)
//
#include <hip/hip_runtime.h>

typedef __attribute__((ext_vector_type(8))) short short8;
typedef __attribute__((ext_vector_type(4))) float f32x4;

#define NW_MASK 511

__device__ __forceinline__ short f2bf(float f) {
  unsigned u = __builtin_bit_cast(unsigned, f);
  u = (u + 0x7fffu + ((u >> 16) & 1u)) >> 16;  // RNE
  return (short)u;
}

// ---------------------------------------------------------------------------
// Prep: gather rpb bias -> bias_f[6][64][64]; pre-transpose + frag-swizzle
// qkv_w (96x288) and proj_w (96x96) into MFMA B-fragment-linear bf16 layout:
// ws*[ (nt*3+ks)*64 + lane ][ j ] = W[ ks*32 + (lane>>4)*8 + j ][ nt*16 + (lane&15) ]
// ---------------------------------------------------------------------------
__global__ void prep_kernel(const float* __restrict__ qkv_w,
                            const float* __restrict__ proj_w,
                            const float* __restrict__ rpb,
                            const int* __restrict__ rel_index,
                            float* __restrict__ bias_f,
                            short* __restrict__ wsq,
                            short* __restrict__ wsp) {
  int idx = blockIdx.x * 256 + threadIdx.x;
  if (idx < 24576) {                       // 6*64*64 bias gather
    int h = idx >> 12;
    int rm = idx & 4095;
    bias_f[idx] = rpb[rel_index[rm] * 6 + h];
  }
  int i2 = idx - 24576;
  if (i2 >= 0 && i2 < 27648) {             // 18 ntiles * 3 ksteps * 64 * 8
    int j = i2 & 7;
    int lane = (i2 >> 3) & 63;
    int frag = i2 >> 9;
    int ks = frag % 3, nt = frag / 3;
    int k = ks * 32 + (lane >> 4) * 8 + j;
    int n = nt * 16 + (lane & 15);
    wsq[i2] = f2bf(qkv_w[k * 288 + n]);
  }
  int i3 = i2 - 27648;
  if (i3 >= 0 && i3 < 9216) {              // 6 ntiles * 3 ksteps * 64 * 8
    int j = i3 & 7;
    int lane = (i3 >> 3) & 63;
    int frag = i3 >> 9;
    int ks = frag % 3, nt = frag / 3;
    int k = ks * 32 + (lane >> 4) * 8 + j;
    int n = nt * 16 + (lane & 15);
    wsp[i3] = f2bf(proj_w[k * 96 + n]);
  }
}

// ---------------------------------------------------------------------------
// Fused window attention: one block per window (8192), 256 threads (4 waves).
// LDS strides padded so row-major b128 frag reads are <=2-way bank conflicts.
// ---------------------------------------------------------------------------
__global__ __launch_bounds__(256) void winattn_kernel(
    const float* __restrict__ x, const float* __restrict__ mask,
    const float* __restrict__ qkv_b, const float* __restrict__ proj_b,
    const float* __restrict__ bias_f, const short* __restrict__ wsq,
    const short* __restrict__ wsp, float* __restrict__ out) {
  // qk: rows 64, cols 0..95 = q (pre-scaled by 0.25), 96..191 = k; stride 200
  __shared__ __align__(16) short qk[64 * 200];   // 25600 B
  __shared__ __align__(16) short vT[96 * 72];    // v transposed [h*16+d][j], 13824 B
  __shared__ __align__(16) short pb[64 * 72];    // softmax P round-trip, 9216 B
  __shared__ __align__(16) short cb[64 * 104];   // attn concat out, 13312 B

  const int b = blockIdx.x;
  const int t = threadIdx.x;
  const int w = t >> 6;        // wave id = m-tile in phases 2/3
  const int l = t & 63;
  const int lm = l & 15;
  const int quad = l >> 4;

  // ---- Phase 1: qkv = x @ Wqkv + b  (A-frags in regs, B-frags from ws) ----
  short8 afr[4][3];
#pragma unroll
  for (int mt = 0; mt < 4; ++mt)
#pragma unroll
    for (int ks = 0; ks < 3; ++ks) {
      const float* xp = x + ((size_t)b * 64 + mt * 16 + lm) * 96 + ks * 32 + quad * 8;
      const float4 u0 = *(const float4*)xp;
      const float4 u1 = *(const float4*)(xp + 4);
      short8 a;
      a[0] = f2bf(u0.x); a[1] = f2bf(u0.y); a[2] = f2bf(u0.z); a[3] = f2bf(u0.w);
      a[4] = f2bf(u1.x); a[5] = f2bf(u1.y); a[6] = f2bf(u1.z); a[7] = f2bf(u1.w);
      afr[mt][ks] = a;
    }

  const short8* wsq8 = (const short8*)wsq;
  // 36 work units = 18 ntiles x 2 m-halves, 9 per wave (balanced)
  for (int u = w * 9; u < w * 9 + 9; ++u) {
    const int nt = u >> 1, mh = (u & 1) * 2;
    short8 bfr[3];
#pragma unroll
    for (int ks = 0; ks < 3; ++ks) bfr[ks] = wsq8[(nt * 3 + ks) * 64 + l];
    const int c = nt * 16 + lm;
    const float bq = qkv_b[c];
    const float sc = (c < 96) ? 0.25f : 1.0f;  // q pre-scale, hd^-0.5 exact
#pragma unroll
    for (int mi = 0; mi < 2; ++mi) {
      const int mt = mh + mi;
      f32x4 acc = {bq, bq, bq, bq};
#pragma unroll
      for (int ks = 0; ks < 3; ++ks)
        acc = __builtin_amdgcn_mfma_f32_16x16x32_bf16(afr[mt][ks], bfr[ks], acc, 0, 0, 0);
#pragma unroll
      for (int i = 0; i < 4; ++i) {
        const int r = mt * 16 + quad * 4 + i;   // C-layout: row = quad*4+reg
        const short v = f2bf(acc[i] * sc);
        if (c < 192) qk[r * 200 + c] = v;
        else vT[(c - 192) * 72 + r] = v;
      }
    }
  }
  __syncthreads();

  // ---- Phase 2: per-head attention, O accumulates in regs ----
  f32x4 oacc[6];
  const int rbase = w * 16 + quad * 4;
  const float* maskp = mask + (size_t)(b & NW_MASK) * 4096;
  for (int h = 0; h < 6; ++h) {
    const f32x4 z4 = {0.f, 0.f, 0.f, 0.f};
    short8 qa = {0, 0, 0, 0, 0, 0, 0, 0};     // k>=16 zero-padded
    if (quad < 2)
      qa = *(const short8*)&qk[(w * 16 + lm) * 200 + h * 16 + quad * 8];
    f32x4 lac[4];
#pragma unroll
    for (int nt = 0; nt < 4; ++nt) {
      short8 kb = {0, 0, 0, 0, 0, 0, 0, 0};
      if (quad < 2)
        kb = *(const short8*)&qk[(nt * 16 + lm) * 200 + 96 + h * 16 + quad * 8];
      lac[nt] = __builtin_amdgcn_mfma_f32_16x16x32_bf16(qa, kb, z4, 0, 0, 0);
    }
    // bias + mask + softmax (row r lives in the 16-lane group sharing quad)
#pragma unroll
    for (int i = 0; i < 4; ++i) {
      const int r = rbase + i;
      const float* bp = bias_f + ((h * 64 + r) << 6);
      const float* mp = maskp + (r << 6);
      float lv[4];
      float mx = -3.0e38f;
#pragma unroll
      for (int nt = 0; nt < 4; ++nt) {
        const int j = nt * 16 + lm;
        lv[nt] = lac[nt][i] + bp[j] + mp[j];
        mx = fmaxf(mx, lv[nt]);
      }
      mx = fmaxf(mx, __shfl_xor(mx, 1));
      mx = fmaxf(mx, __shfl_xor(mx, 2));
      mx = fmaxf(mx, __shfl_xor(mx, 4));
      mx = fmaxf(mx, __shfl_xor(mx, 8));
      float sm = 0.f;
#pragma unroll
      for (int nt = 0; nt < 4; ++nt) { lv[nt] = __expf(lv[nt] - mx); sm += lv[nt]; }
      sm += __shfl_xor(sm, 1);
      sm += __shfl_xor(sm, 2);
      sm += __shfl_xor(sm, 4);
      sm += __shfl_xor(sm, 8);
      const float inv = 1.0f / sm;
#pragma unroll
      for (int nt = 0; nt < 4; ++nt)
        pb[r * 72 + nt * 16 + lm] = f2bf(lv[nt] * inv);
    }
    __syncthreads();  // cross-lane LDS visibility (C-layout -> A-layout)
    // PV: O[r][d] += P[r][j] V[j][d], K=64 in 2 steps
    f32x4 oa = {0.f, 0.f, 0.f, 0.f};
#pragma unroll
    for (int ks = 0; ks < 2; ++ks) {
      const short8 pa = *(const short8*)&pb[(w * 16 + lm) * 72 + ks * 32 + quad * 8];
      const short8 vb = *(const short8*)&vT[(h * 16 + lm) * 72 + ks * 32 + quad * 8];
      oa = __builtin_amdgcn_mfma_f32_16x16x32_bf16(pa, vb, oa, 0, 0, 0);
    }
    oacc[h] = oa;
    __syncthreads();  // WAR: pb rewritten next head
  }

  // ---- Phase 3: out = concat(O) @ proj_w + b ----
#pragma unroll
  for (int h = 0; h < 6; ++h)
#pragma unroll
    for (int i = 0; i < 4; ++i)
      cb[(rbase + i) * 104 + h * 16 + lm] = f2bf(oacc[h][i]);
  __syncthreads();

  short8 ca[3];
#pragma unroll
  for (int ks = 0; ks < 3; ++ks)
    ca[ks] = *(const short8*)&cb[(w * 16 + lm) * 104 + ks * 32 + quad * 8];

  const short8* wsp8 = (const short8*)wsp;
  float* outp = out + (size_t)b * 64 * 96;
#pragma unroll
  for (int nt = 0; nt < 6; ++nt) {
    short8 pw[3];
#pragma unroll
    for (int ks = 0; ks < 3; ++ks) pw[ks] = wsp8[(nt * 3 + ks) * 64 + l];
    const float bp = proj_b[nt * 16 + lm];
    f32x4 acc = {bp, bp, bp, bp};
#pragma unroll
    for (int ks = 0; ks < 3; ++ks)
      acc = __builtin_amdgcn_mfma_f32_16x16x32_bf16(ca[ks], pw[ks], acc, 0, 0, 0);
#pragma unroll
    for (int i = 0; i < 4; ++i)
      outp[(rbase + i) * 96 + nt * 16 + lm] = acc[i];
  }
}

extern "C" void kernel_launch(void* const* d_in, const int* in_sizes, int n_in,
                              void* d_out, int out_size, void* d_ws, size_t ws_size,
                              hipStream_t stream) {
  const float* x      = (const float*)d_in[0];
  const float* mask   = (const float*)d_in[1];
  const float* qkv_w  = (const float*)d_in[2];
  const float* qkv_b  = (const float*)d_in[3];
  const float* proj_w = (const float*)d_in[4];
  const float* proj_b = (const float*)d_in[5];
  const float* rpb    = (const float*)d_in[6];
  const int*   rel    = (const int*)d_in[7];

  float* bias_f = (float*)d_ws;                               // 98304 B
  short* wsq    = (short*)((char*)d_ws + 98304);              // 55296 B
  short* wsp    = (short*)((char*)d_ws + 98304 + 55296);      // 18432 B

  hipLaunchKernelGGL(prep_kernel, dim3(240), dim3(256), 0, stream,
                     qkv_w, proj_w, rpb, rel, bias_f, wsq, wsp);
  hipLaunchKernelGGL(winattn_kernel, dim3(8192), dim3(256), 0, stream,
                     x, mask, qkv_b, proj_b, bias_f, wsq, wsp, (float*)d_out);
}